// Round 1
// baseline (8354.178 us; speedup 1.0000x reference)
//
#include <hip/hip_runtime.h>

// Problem constants (match reference setup_inputs)
constexpr int NN = 50000;     // nodes
constexpr int NE = 1600000;   // edges
constexpr int H  = 128;       // feature dim (F_IN == H)
constexpr int LH = 256;       // lstm hidden
constexpr int OD = 32;        // output dim
constexpr int NG = 64;        // graphs

// ---------------------------------------------------------------- degree
__global__ __launch_bounds__(256) void k_deg(const int* __restrict__ col,
                                             float* __restrict__ deg) {
    int i = blockIdx.x * 256 + threadIdx.x;
    if (i < NE) atomicAdd(&deg[col[i]], 1.0f);
}

// deg -> dinv = rsqrt(deg + 1)  (self-loop adds 1; always > 0)
__global__ __launch_bounds__(256) void k_dinv(float* __restrict__ deg) {
    int i = blockIdx.x * 256 + threadIdx.x;
    if (i < NN) deg[i] = rsqrtf(deg[i] + 1.0f);
}

// per-edge norm = dinv[row] * dinv[col]   (reused across all 3 layers)
__global__ __launch_bounds__(256) void k_norm(const int* __restrict__ ei,
                                              const float* __restrict__ dinv,
                                              float* __restrict__ norm) {
    int e = blockIdx.x * 256 + threadIdx.x;
    if (e < NE) norm[e] = dinv[ei[e]] * dinv[ei[NE + e]];
}

// ---------------------------------------------------------------- GEMM t = h @ W  ([NN x 128] @ [128 x 128])
// Block = 256 threads (4 waves), 64 rows per block.
// Thread: 8 rows x 4 cols. W rows read coalesced (32 lanes x float4 = full
// 512B row); h reads broadcast across half-wave. No LDS needed.
template <bool RELU>
__global__ __launch_bounds__(256) void k_gemm(const float* __restrict__ h,
                                              const float* __restrict__ W,
                                              float* __restrict__ t) {
    const int tid  = threadIdx.x;
    const int lane = tid & 63;
    const int wave = tid >> 6;
    const int colg = lane & 31;                 // 0..31 -> cols colg*4..+3
    const int rowg = (wave << 1) | (lane >> 5); // 0..7  -> 8 rows each
    const int rb   = blockIdx.x * 64 + rowg * 8;

    const float4* __restrict__ W4 = reinterpret_cast<const float4*>(W);

    float4 acc[8];
#pragma unroll
    for (int r = 0; r < 8; ++r) acc[r] = make_float4(0.f, 0.f, 0.f, 0.f);

    int rowid[8];
#pragma unroll
    for (int r = 0; r < 8; ++r) {
        int rr   = rb + r;
        rowid[r] = rr < NN ? rr : NN - 1;   // clamp loads, guard stores
    }

    for (int k0 = 0; k0 < H; k0 += 4) {
        float4 wv0 = W4[(k0 + 0) * 32 + colg];
        float4 wv1 = W4[(k0 + 1) * 32 + colg];
        float4 wv2 = W4[(k0 + 2) * 32 + colg];
        float4 wv3 = W4[(k0 + 3) * 32 + colg];
#pragma unroll
        for (int r = 0; r < 8; ++r) {
            float4 hv = *reinterpret_cast<const float4*>(h + (size_t)rowid[r] * H + k0);
            if (RELU) {
                hv.x = fmaxf(hv.x, 0.f); hv.y = fmaxf(hv.y, 0.f);
                hv.z = fmaxf(hv.z, 0.f); hv.w = fmaxf(hv.w, 0.f);
            }
            acc[r].x = fmaf(hv.x, wv0.x, fmaf(hv.y, wv1.x, fmaf(hv.z, wv2.x, fmaf(hv.w, wv3.x, acc[r].x))));
            acc[r].y = fmaf(hv.x, wv0.y, fmaf(hv.y, wv1.y, fmaf(hv.z, wv2.y, fmaf(hv.w, wv3.y, acc[r].y))));
            acc[r].z = fmaf(hv.x, wv0.z, fmaf(hv.y, wv1.z, fmaf(hv.z, wv2.z, fmaf(hv.w, wv3.z, acc[r].z))));
            acc[r].w = fmaf(hv.x, wv0.w, fmaf(hv.y, wv1.w, fmaf(hv.z, wv2.w, fmaf(hv.w, wv3.w, acc[r].w))));
        }
    }

#pragma unroll
    for (int r = 0; r < 8; ++r) {
        int rr = rb + r;
        if (rr < NN)
            *reinterpret_cast<float4*>(t + (size_t)rr * H + colg * 4) = acc[r];
    }
}

// ---------------------------------------------------------------- agg init: agg = bg + t * dinv^2  (bias + self-loop fused)
__global__ __launch_bounds__(256) void k_init(const float* __restrict__ t,
                                              const float* __restrict__ dinv,
                                              const float* __restrict__ bg,
                                              float* __restrict__ agg) {
    int i = blockIdx.x * 256 + threadIdx.x;   // over NN*32 float4 groups
    if (i >= NN * 32) return;
    int n = i >> 5, j4 = i & 31;
    float d = dinv[n];
    float s = d * d;
    float4 tv = reinterpret_cast<const float4*>(t)[i];
    float4 b  = reinterpret_cast<const float4*>(bg)[j4];
    float4 o;
    o.x = fmaf(tv.x, s, b.x);
    o.y = fmaf(tv.y, s, b.y);
    o.z = fmaf(tv.z, s, b.z);
    o.w = fmaf(tv.w, s, b.w);
    reinterpret_cast<float4*>(agg)[i] = o;
}

// ---------------------------------------------------------------- edge scatter: agg[col] += t[row] * norm
// 2 edges per wave: half-wave (32 lanes x float4) covers the 512B feature row.
__global__ __launch_bounds__(256) void k_scatter(const int* __restrict__ ei,
                                                 const float* __restrict__ norm,
                                                 const float* __restrict__ t,
                                                 float* __restrict__ agg) {
    int gtid = blockIdx.x * 256 + threadIdx.x;
    int wv   = gtid >> 6;
    int lane = gtid & 63;
    int half = lane >> 5;
    int l32  = lane & 31;
    int nw   = (gridDim.x * 256) >> 6;
    const float4* __restrict__ t4 = reinterpret_cast<const float4*>(t);
    for (int p = wv; p < NE / 2; p += nw) {
        int e = p * 2 + half;
        int r = ei[e];
        int c = ei[NE + e];
        float nm = norm[e];
        float4 v = t4[(size_t)r * 32 + l32];
        float* a = agg + (size_t)c * H + l32 * 4;
        atomicAdd(a + 0, v.x * nm);
        atomicAdd(a + 1, v.y * nm);
        atomicAdd(a + 2, v.z * nm);
        atomicAdd(a + 3, v.w * nm);
    }
}

// ---------------------------------------------------------------- mean pool (batch is sorted -> binary search segment bounds)
__device__ __forceinline__ int lower_bound_dev(const int* __restrict__ b, int v) {
    int lo = 0, hi = NN;
    while (lo < hi) {
        int m = (lo + hi) >> 1;
        if (b[m] < v) lo = m + 1; else hi = m;
    }
    return lo;
}

__global__ __launch_bounds__(128) void k_pool(const int* __restrict__ batch,
                                              const float* __restrict__ agg,
                                              float* __restrict__ pooled,
                                              float* __restrict__ cnt) {
    int g = blockIdx.x >> 3;   // 8 blocks per graph
    int q = blockIdx.x & 7;
    int tid = threadIdx.x;     // feature index
    int s = lower_bound_dev(batch, g);
    int e = lower_bound_dev(batch, g + 1);
    float sum = 0.f;
    for (int n = s + q; n < e; n += 8)
        sum += fmaxf(agg[(size_t)n * H + tid], 0.f);   // ReLU fused
    atomicAdd(&pooled[g * H + tid], sum);
    if (q == 0 && tid == 0) cnt[g] = (float)(e - s);
}

// ---------------------------------------------------------------- LSTM (single step, h0=c0=0) + output head, fused
__global__ __launch_bounds__(256) void k_lstm(const float* __restrict__ pooled,
                                              const float* __restrict__ cnt,
                                              const float* __restrict__ W_ih,
                                              const float* __restrict__ b_ih,
                                              const float* __restrict__ b_hh,
                                              const float* __restrict__ W_out,
                                              const float* __restrict__ b_out,
                                              float* __restrict__ out) {
    __shared__ __align__(16) float p[H];
    __shared__ __align__(16) float hn[LH];
    int g = blockIdx.x, t = threadIdx.x;
    if (t < H) p[t] = pooled[g * H + t] / fmaxf(cnt[g], 1.f);
    __syncthreads();

    // gate rows (torch order i,f,g,o): i=t, g=2*LH+t, o=3*LH+t. f unused (c0=0).
    float si = b_ih[t] + b_hh[t];
    float sg = b_ih[2 * LH + t] + b_hh[2 * LH + t];
    float so = b_ih[3 * LH + t] + b_hh[3 * LH + t];
    const float* wi = W_ih + (size_t)t * H;
    const float* wg = W_ih + (size_t)(2 * LH + t) * H;
    const float* wo = W_ih + (size_t)(3 * LH + t) * H;
    for (int k = 0; k < H; k += 4) {
        float4 pv = *reinterpret_cast<const float4*>(&p[k]);
        float4 a = *reinterpret_cast<const float4*>(wi + k);
        si += pv.x * a.x + pv.y * a.y + pv.z * a.z + pv.w * a.w;
        float4 b = *reinterpret_cast<const float4*>(wg + k);
        sg += pv.x * b.x + pv.y * b.y + pv.z * b.z + pv.w * b.w;
        float4 c = *reinterpret_cast<const float4*>(wo + k);
        so += pv.x * c.x + pv.y * c.y + pv.z * c.z + pv.w * c.w;
    }
    float ig = 1.f / (1.f + expf(-si));
    float cc = ig * tanhf(sg);
    float og = 1.f / (1.f + expf(-so));
    hn[t] = og * tanhf(cc);
    __syncthreads();

    if (t < OD) {
        float acc = b_out[t];
        const float* wr = W_out + (size_t)t * LH;
        for (int k = 0; k < LH; k += 4) {
            float4 hv = *reinterpret_cast<const float4*>(&hn[k]);
            float4 wv = *reinterpret_cast<const float4*>(wr + k);
            acc += hv.x * wv.x + hv.y * wv.y + hv.z * wv.z + hv.w * wv.w;
        }
        out[g * OD + t] = acc;
    }
}

// ----------------------------------------------------------------
extern "C" void kernel_launch(void* const* d_in, const int* in_sizes, int n_in,
                              void* d_out, int out_size, void* d_ws, size_t ws_size,
                              hipStream_t stream) {
    const float* x     = (const float*)d_in[0];
    const int*   ei    = (const int*)d_in[1];   // [2][NE]: rows then cols
    const int*   batch = (const int*)d_in[2];
    const float* Wg    = (const float*)d_in[3]; // [3][128][128]
    const float* bg    = (const float*)d_in[4]; // [3][128]
    const float* W_ih  = (const float*)d_in[5]; // [1024][128]
    const float* b_ih  = (const float*)d_in[7];
    const float* b_hh  = (const float*)d_in[8];
    const float* W_out = (const float*)d_in[9]; // [32][256]
    const float* b_out = (const float*)d_in[10];
    float* out = (float*)d_out;

    // workspace layout (floats): ~83.4 MB total
    float* ws     = (float*)d_ws;
    float* t      = ws;                          // NN*H
    float* aggA   = t    + (size_t)NN * H;       // NN*H
    float* aggB   = aggA + (size_t)NN * H;       // NN*H
    float* dinv   = aggB + (size_t)NN * H;       // NN (deg, then rsqrt in-place)
    float* norm   = dinv + NN;                   // NE
    float* pooled = norm + NE;                   // NG*H
    float* cnt    = pooled + NG * H;             // NG

    hipMemsetAsync(dinv, 0, NN * sizeof(float), stream);
    hipMemsetAsync(pooled, 0, (NG * H + NG) * sizeof(float), stream);

    k_deg<<<(NE + 255) / 256, 256, 0, stream>>>(ei + NE, dinv);
    k_dinv<<<(NN + 255) / 256, 256, 0, stream>>>(dinv);
    k_norm<<<(NE + 255) / 256, 256, 0, stream>>>(ei, dinv, norm);

    const int gemmBlocks = (NN + 63) / 64;
    const int initBlocks = (NN * 32 + 255) / 256;
    const int scatBlocks = 2048;

    // layer 0: x -> t -> aggA
    k_gemm<false><<<gemmBlocks, 256, 0, stream>>>(x, Wg, t);
    k_init<<<initBlocks, 256, 0, stream>>>(t, dinv, bg, aggA);
    k_scatter<<<scatBlocks, 256, 0, stream>>>(ei, norm, t, aggA);
    // layer 1: relu(aggA) -> t -> aggB
    k_gemm<true><<<gemmBlocks, 256, 0, stream>>>(aggA, Wg + H * H, t);
    k_init<<<initBlocks, 256, 0, stream>>>(t, dinv, bg + H, aggB);
    k_scatter<<<scatBlocks, 256, 0, stream>>>(ei, norm, t, aggB);
    // layer 2: relu(aggB) -> t -> aggA
    k_gemm<true><<<gemmBlocks, 256, 0, stream>>>(aggB, Wg + 2 * H * H, t);
    k_init<<<initBlocks, 256, 0, stream>>>(t, dinv, bg + 2 * H, aggA);
    k_scatter<<<scatBlocks, 256, 0, stream>>>(ei, norm, t, aggA);

    k_pool<<<NG * 8, 128, 0, stream>>>(batch, aggA, pooled, cnt);
    k_lstm<<<NG, 256, 0, stream>>>(pooled, cnt, W_ih, b_ih, b_hh, W_out, b_out, out);
}

// Round 2
// 728.531 us; speedup vs baseline: 11.4672x; 11.4672x over previous
//
#include <hip/hip_runtime.h>

// Problem constants (match reference setup_inputs)
constexpr int NN = 50000;     // nodes
constexpr int NE = 1600000;   // edges
constexpr int H  = 128;       // feature dim (F_IN == H)
constexpr int LH = 256;       // lstm hidden
constexpr int OD = 32;        // output dim
constexpr int NG = 64;        // graphs
constexpr int NB = (NN + 255) / 256;  // scan blocks = 196

// ---------------------------------------------------------------- CSR build
// in-degree histogram (int atomics, cheap vs fp atomics)
__global__ __launch_bounds__(256) void k_hist(const int* __restrict__ col,
                                              int* __restrict__ cnt) {
    int i = blockIdx.x * 256 + threadIdx.x;
    if (i < NE) atomicAdd(&cnt[col[i]], 1);
}

// dinv = rsqrt(indeg + 1)  (self-loop adds 1; always > 0)
__global__ __launch_bounds__(256) void k_dinv(const int* __restrict__ cnt,
                                              float* __restrict__ dinv) {
    int i = blockIdx.x * 256 + threadIdx.x;
    if (i < NN) dinv[i] = rsqrtf((float)cnt[i] + 1.0f);
}

// scan stage 1: per-block sums of cnt
__global__ __launch_bounds__(256) void k_scan1(const int* __restrict__ cnt,
                                               int* __restrict__ bsum) {
    __shared__ int sh[256];
    int b = blockIdx.x, t = threadIdx.x, i = b * 256 + t;
    sh[t] = (i < NN) ? cnt[i] : 0;
    __syncthreads();
    for (int off = 128; off > 0; off >>= 1) {
        if (t < off) sh[t] += sh[t + off];
        __syncthreads();
    }
    if (t == 0) bsum[b] = sh[0];
}

// scan stage 2: exclusive scan of block sums (serial, NB=196 tiny)
__global__ __launch_bounds__(64) void k_scan2(const int* __restrict__ bsum,
                                              int* __restrict__ boff) {
    if (threadIdx.x == 0) {
        int run = 0;
        for (int b = 0; b < NB; ++b) { boff[b] = run; run += bsum[b]; }
    }
}

// scan stage 3: in-block exclusive scan + block offset -> rp, cursor
__global__ __launch_bounds__(256) void k_scan3(const int* __restrict__ cnt,
                                               const int* __restrict__ boff,
                                               int* __restrict__ rp,
                                               int* __restrict__ cursor) {
    __shared__ int sh[256];
    int b = blockIdx.x, t = threadIdx.x, i = b * 256 + t;
    int v = (i < NN) ? cnt[i] : 0;
    sh[t] = v;
    __syncthreads();
    for (int off = 1; off < 256; off <<= 1) {
        int add = (t >= off) ? sh[t - off] : 0;
        __syncthreads();
        sh[t] += add;
        __syncthreads();
    }
    if (i < NN) {
        int excl = sh[t] - v + boff[b];
        rp[i] = excl;
        cursor[i] = excl;
    }
}

// fill CSR: srcs[pos] = row, norms[pos] = dinv[row]*dinv[col]
__global__ __launch_bounds__(256) void k_fill(const int* __restrict__ ei,
                                              const float* __restrict__ dinv,
                                              int* __restrict__ cursor,
                                              int* __restrict__ srcs,
                                              float* __restrict__ norms) {
    int e = blockIdx.x * 256 + threadIdx.x;
    if (e >= NE) return;
    int r = ei[e];
    int c = ei[NE + e];
    int pos = atomicAdd(&cursor[c], 1);
    srcs[pos] = r;
    norms[pos] = dinv[r] * dinv[c];
}

// ---------------------------------------------------------------- GEMM t = h @ W  ([NN x 128] @ [128 x 128])
// Block = 256 threads (4 waves), 64 rows per block. Thread: 8 rows x 4 cols.
template <bool RELU>
__global__ __launch_bounds__(256) void k_gemm(const float* __restrict__ h,
                                              const float* __restrict__ W,
                                              float* __restrict__ t) {
    const int tid  = threadIdx.x;
    const int lane = tid & 63;
    const int wave = tid >> 6;
    const int colg = lane & 31;                 // 0..31 -> cols colg*4..+3
    const int rowg = (wave << 1) | (lane >> 5); // 0..7  -> 8 rows each
    const int rb   = blockIdx.x * 64 + rowg * 8;

    const float4* __restrict__ W4 = reinterpret_cast<const float4*>(W);

    float4 acc[8];
#pragma unroll
    for (int r = 0; r < 8; ++r) acc[r] = make_float4(0.f, 0.f, 0.f, 0.f);

    int rowid[8];
#pragma unroll
    for (int r = 0; r < 8; ++r) {
        int rr   = rb + r;
        rowid[r] = rr < NN ? rr : NN - 1;   // clamp loads, guard stores
    }

    for (int k0 = 0; k0 < H; k0 += 4) {
        float4 wv0 = W4[(k0 + 0) * 32 + colg];
        float4 wv1 = W4[(k0 + 1) * 32 + colg];
        float4 wv2 = W4[(k0 + 2) * 32 + colg];
        float4 wv3 = W4[(k0 + 3) * 32 + colg];
#pragma unroll
        for (int r = 0; r < 8; ++r) {
            float4 hv = *reinterpret_cast<const float4*>(h + (size_t)rowid[r] * H + k0);
            if (RELU) {
                hv.x = fmaxf(hv.x, 0.f); hv.y = fmaxf(hv.y, 0.f);
                hv.z = fmaxf(hv.z, 0.f); hv.w = fmaxf(hv.w, 0.f);
            }
            acc[r].x = fmaf(hv.x, wv0.x, fmaf(hv.y, wv1.x, fmaf(hv.z, wv2.x, fmaf(hv.w, wv3.x, acc[r].x))));
            acc[r].y = fmaf(hv.x, wv0.y, fmaf(hv.y, wv1.y, fmaf(hv.z, wv2.y, fmaf(hv.w, wv3.y, acc[r].y))));
            acc[r].z = fmaf(hv.x, wv0.z, fmaf(hv.y, wv1.z, fmaf(hv.z, wv2.z, fmaf(hv.w, wv3.z, acc[r].z))));
            acc[r].w = fmaf(hv.x, wv0.w, fmaf(hv.y, wv1.w, fmaf(hv.z, wv2.w, fmaf(hv.w, wv3.w, acc[r].w))));
        }
    }

#pragma unroll
    for (int r = 0; r < 8; ++r) {
        int rr = rb + r;
        if (rr < NN)
            *reinterpret_cast<float4*>(t + (size_t)rr * H + colg * 4) = acc[r];
    }
}

// ---------------------------------------------------------------- gather: agg[n] = bg + t[n]*dinv[n]^2 + sum_e t[src[e]]*norm[e]
// Half-wave (32 lanes x float4) per node; edge rows read from L2/L3.
__global__ __launch_bounds__(256) void k_gather(const int* __restrict__ rp,
                                                const int* __restrict__ cnt,
                                                const int* __restrict__ srcs,
                                                const float* __restrict__ norms,
                                                const float* __restrict__ dinv,
                                                const float* __restrict__ bg,
                                                const float* __restrict__ t,
                                                float* __restrict__ agg) {
    const int tid = threadIdx.x;
    const int n   = blockIdx.x * 8 + (tid >> 5);
    const int l32 = tid & 31;
    if (n >= NN) return;

    const float4* __restrict__ t4 = reinterpret_cast<const float4*>(t);
    float d = dinv[n];
    float s = d * d;
    float4 tv = t4[(size_t)n * 32 + l32];
    float4 b  = reinterpret_cast<const float4*>(bg)[l32];
    float4 acc;
    acc.x = fmaf(tv.x, s, b.x);
    acc.y = fmaf(tv.y, s, b.y);
    acc.z = fmaf(tv.z, s, b.z);
    acc.w = fmaf(tv.w, s, b.w);

    int i = rp[n];
    const int e = i + cnt[n];
    for (; i + 3 < e; i += 4) {
        int s0 = srcs[i], s1 = srcs[i + 1], s2 = srcs[i + 2], s3 = srcs[i + 3];
        float n0 = norms[i], n1 = norms[i + 1], n2 = norms[i + 2], n3 = norms[i + 3];
        float4 v0 = t4[(size_t)s0 * 32 + l32];
        float4 v1 = t4[(size_t)s1 * 32 + l32];
        float4 v2 = t4[(size_t)s2 * 32 + l32];
        float4 v3 = t4[(size_t)s3 * 32 + l32];
        acc.x = fmaf(v0.x, n0, acc.x); acc.y = fmaf(v0.y, n0, acc.y);
        acc.z = fmaf(v0.z, n0, acc.z); acc.w = fmaf(v0.w, n0, acc.w);
        acc.x = fmaf(v1.x, n1, acc.x); acc.y = fmaf(v1.y, n1, acc.y);
        acc.z = fmaf(v1.z, n1, acc.z); acc.w = fmaf(v1.w, n1, acc.w);
        acc.x = fmaf(v2.x, n2, acc.x); acc.y = fmaf(v2.y, n2, acc.y);
        acc.z = fmaf(v2.z, n2, acc.z); acc.w = fmaf(v2.w, n2, acc.w);
        acc.x = fmaf(v3.x, n3, acc.x); acc.y = fmaf(v3.y, n3, acc.y);
        acc.z = fmaf(v3.z, n3, acc.z); acc.w = fmaf(v3.w, n3, acc.w);
    }
    for (; i < e; ++i) {
        int s0 = srcs[i];
        float n0 = norms[i];
        float4 v0 = t4[(size_t)s0 * 32 + l32];
        acc.x = fmaf(v0.x, n0, acc.x); acc.y = fmaf(v0.y, n0, acc.y);
        acc.z = fmaf(v0.z, n0, acc.z); acc.w = fmaf(v0.w, n0, acc.w);
    }

    reinterpret_cast<float4*>(agg)[(size_t)n * 32 + l32] = acc;
}

// ---------------------------------------------------------------- mean pool (batch sorted -> binary search bounds)
__device__ __forceinline__ int lower_bound_dev(const int* __restrict__ b, int v) {
    int lo = 0, hi = NN;
    while (lo < hi) {
        int m = (lo + hi) >> 1;
        if (b[m] < v) lo = m + 1; else hi = m;
    }
    return lo;
}

__global__ __launch_bounds__(128) void k_pool(const int* __restrict__ batch,
                                              const float* __restrict__ agg,
                                              float* __restrict__ pooled,
                                              float* __restrict__ gcnt) {
    int g = blockIdx.x >> 3;   // 8 blocks per graph
    int q = blockIdx.x & 7;
    int tid = threadIdx.x;     // feature index
    int s = lower_bound_dev(batch, g);
    int e = lower_bound_dev(batch, g + 1);
    float sum = 0.f;
    for (int n = s + q; n < e; n += 8)
        sum += fmaxf(agg[(size_t)n * H + tid], 0.f);   // ReLU fused
    atomicAdd(&pooled[g * H + tid], sum);
    if (q == 0 && tid == 0) gcnt[g] = (float)(e - s);
}

// ---------------------------------------------------------------- LSTM (single step, h0=c0=0) + output head, fused
__global__ __launch_bounds__(256) void k_lstm(const float* __restrict__ pooled,
                                              const float* __restrict__ gcnt,
                                              const float* __restrict__ W_ih,
                                              const float* __restrict__ b_ih,
                                              const float* __restrict__ b_hh,
                                              const float* __restrict__ W_out,
                                              const float* __restrict__ b_out,
                                              float* __restrict__ out) {
    __shared__ __align__(16) float p[H];
    __shared__ __align__(16) float hn[LH];
    int g = blockIdx.x, t = threadIdx.x;
    if (t < H) p[t] = pooled[g * H + t] / fmaxf(gcnt[g], 1.f);
    __syncthreads();

    // gate rows (torch order i,f,g,o): f unused (c0=0)
    float si = b_ih[t] + b_hh[t];
    float sg = b_ih[2 * LH + t] + b_hh[2 * LH + t];
    float so = b_ih[3 * LH + t] + b_hh[3 * LH + t];
    const float* wi = W_ih + (size_t)t * H;
    const float* wg = W_ih + (size_t)(2 * LH + t) * H;
    const float* wo = W_ih + (size_t)(3 * LH + t) * H;
    for (int k = 0; k < H; k += 4) {
        float4 pv = *reinterpret_cast<const float4*>(&p[k]);
        float4 a = *reinterpret_cast<const float4*>(wi + k);
        si += pv.x * a.x + pv.y * a.y + pv.z * a.z + pv.w * a.w;
        float4 b = *reinterpret_cast<const float4*>(wg + k);
        sg += pv.x * b.x + pv.y * b.y + pv.z * b.z + pv.w * b.w;
        float4 c = *reinterpret_cast<const float4*>(wo + k);
        so += pv.x * c.x + pv.y * c.y + pv.z * c.z + pv.w * c.w;
    }
    float ig = 1.f / (1.f + expf(-si));
    float cc = ig * tanhf(sg);
    float og = 1.f / (1.f + expf(-so));
    hn[t] = og * tanhf(cc);
    __syncthreads();

    if (t < OD) {
        float acc = b_out[t];
        const float* wr = W_out + (size_t)t * LH;
        for (int k = 0; k < LH; k += 4) {
            float4 hv = *reinterpret_cast<const float4*>(&hn[k]);
            float4 wv = *reinterpret_cast<const float4*>(wr + k);
            acc += hv.x * wv.x + hv.y * wv.y + hv.z * wv.z + hv.w * wv.w;
        }
        out[g * OD + t] = acc;
    }
}

// ----------------------------------------------------------------
extern "C" void kernel_launch(void* const* d_in, const int* in_sizes, int n_in,
                              void* d_out, int out_size, void* d_ws, size_t ws_size,
                              hipStream_t stream) {
    const float* x     = (const float*)d_in[0];
    const int*   ei    = (const int*)d_in[1];   // [2][NE]: rows then cols
    const int*   batch = (const int*)d_in[2];
    const float* Wg    = (const float*)d_in[3]; // [3][128][128]
    const float* bg    = (const float*)d_in[4]; // [3][128]
    const float* W_ih  = (const float*)d_in[5]; // [1024][128]
    const float* b_ih  = (const float*)d_in[7];
    const float* b_hh  = (const float*)d_in[8];
    const float* W_out = (const float*)d_in[9]; // [32][256]
    const float* b_out = (const float*)d_in[10];
    float* out = (float*)d_out;

    // workspace layout (~65 MB)
    float* ws     = (float*)d_ws;
    float* buf0   = ws;                          // NN*H  (t)
    float* buf1   = buf0 + (size_t)NN * H;       // NN*H  (agg)
    float* dinv   = buf1 + (size_t)NN * H;       // NN
    float* norms  = dinv + NN;                   // NE
    float* pooled = norms + NE;                  // NG*H
    float* gcnt   = pooled + NG * H;             // NG
    int*   cnt    = (int*)(gcnt + NG);           // NN
    int*   rp     = cnt + NN;                    // NN
    int*   cursor = rp + NN;                     // NN
    int*   srcs   = cursor + NN;                 // NE
    int*   bsum   = srcs + NE;                   // NB
    int*   boff   = bsum + 256;                  // NB

    hipMemsetAsync(cnt, 0, NN * sizeof(int), stream);
    hipMemsetAsync(pooled, 0, (NG * H + NG) * sizeof(float), stream);

    const int eBlocks = (NE + 255) / 256;
    const int nBlocks = (NN + 255) / 256;

    // CSR build (by destination) + norms
    k_hist <<<eBlocks, 256, 0, stream>>>(ei + NE, cnt);
    k_dinv <<<nBlocks, 256, 0, stream>>>(cnt, dinv);
    k_scan1<<<NB, 256, 0, stream>>>(cnt, bsum);
    k_scan2<<<1, 64, 0, stream>>>(bsum, boff);
    k_scan3<<<NB, 256, 0, stream>>>(cnt, boff, rp, cursor);
    k_fill <<<eBlocks, 256, 0, stream>>>(ei, dinv, cursor, srcs, norms);

    const int gemmBlocks = (NN + 63) / 64;
    const int gathBlocks = (NN + 7) / 8;

    // layer 0: x -> buf0 -> buf1
    k_gemm<false><<<gemmBlocks, 256, 0, stream>>>(x, Wg, buf0);
    k_gather<<<gathBlocks, 256, 0, stream>>>(rp, cnt, srcs, norms, dinv, bg, buf0, buf1);
    // layer 1: relu(buf1) -> buf0 -> buf1
    k_gemm<true><<<gemmBlocks, 256, 0, stream>>>(buf1, Wg + H * H, buf0);
    k_gather<<<gathBlocks, 256, 0, stream>>>(rp, cnt, srcs, norms, dinv, bg + H, buf0, buf1);
    // layer 2: relu(buf1) -> buf0 -> buf1
    k_gemm<true><<<gemmBlocks, 256, 0, stream>>>(buf1, Wg + 2 * H * H, buf0);
    k_gather<<<gathBlocks, 256, 0, stream>>>(rp, cnt, srcs, norms, dinv, bg + 2 * H, buf0, buf1);

    k_pool<<<NG * 8, 128, 0, stream>>>(batch, buf1, pooled, gcnt);
    k_lstm<<<NG, 256, 0, stream>>>(pooled, gcnt, W_ih, b_ih, b_hh, W_out, b_out, out);
}

// Round 3
// 727.710 us; speedup vs baseline: 11.4801x; 1.0011x over previous
//
#include <hip/hip_runtime.h>

// Problem constants (match reference setup_inputs)
constexpr int NN = 50000;     // nodes
constexpr int NE = 1600000;   // edges
constexpr int H  = 128;       // feature dim (F_IN == H)
constexpr int LH = 256;       // lstm hidden
constexpr int OD = 32;        // output dim
constexpr int NG = 64;        // graphs
constexpr int NB = (NN + 255) / 256;  // scan blocks = 196 (must be <= 256)
static_assert(NB <= 256, "k_scan2 assumes NB <= 256");

// ---------------------------------------------------------------- CSR build
// in-degree histogram (int atomics)
__global__ __launch_bounds__(256) void k_hist(const int* __restrict__ col,
                                              int* __restrict__ cnt) {
    int i = blockIdx.x * 256 + threadIdx.x;
    if (i < NE) atomicAdd(&cnt[col[i]], 1);
}

// scan stage 1: per-block sums of cnt
__global__ __launch_bounds__(256) void k_scan1(const int* __restrict__ cnt,
                                               int* __restrict__ bsum) {
    __shared__ int sh[256];
    int b = blockIdx.x, t = threadIdx.x, i = b * 256 + t;
    sh[t] = (i < NN) ? cnt[i] : 0;
    __syncthreads();
    for (int off = 128; off > 0; off >>= 1) {
        if (t < off) sh[t] += sh[t + off];
        __syncthreads();
    }
    if (t == 0) bsum[b] = sh[0];
}

// scan stage 2: exclusive scan of block sums — single-block parallel scan
__global__ __launch_bounds__(256) void k_scan2(const int* __restrict__ bsum,
                                               int* __restrict__ boff) {
    __shared__ int sh[256];
    int t = threadIdx.x;
    int v = (t < NB) ? bsum[t] : 0;
    sh[t] = v;
    __syncthreads();
    for (int off = 1; off < 256; off <<= 1) {
        int add = (t >= off) ? sh[t - off] : 0;
        __syncthreads();
        sh[t] += add;
        __syncthreads();
    }
    if (t < NB) boff[t] = sh[t] - v;   // exclusive
}

// scan stage 3: in-block exclusive scan + block offset -> rp, cursor; also dinv
__global__ __launch_bounds__(256) void k_scan3(const int* __restrict__ cnt,
                                               const int* __restrict__ boff,
                                               int* __restrict__ rp,
                                               int* __restrict__ cursor,
                                               float* __restrict__ dinv) {
    __shared__ int sh[256];
    int b = blockIdx.x, t = threadIdx.x, i = b * 256 + t;
    int v = (i < NN) ? cnt[i] : 0;
    sh[t] = v;
    __syncthreads();
    for (int off = 1; off < 256; off <<= 1) {
        int add = (t >= off) ? sh[t - off] : 0;
        __syncthreads();
        sh[t] += add;
        __syncthreads();
    }
    if (i < NN) {
        int excl = sh[t] - v + boff[b];
        rp[i] = excl;
        cursor[i] = excl;
        dinv[i] = rsqrtf((float)v + 1.0f);   // self-loop adds 1
    }
}

// fill CSR: srcs[pos] = row  (norm is separable -> no norms array at all)
__global__ __launch_bounds__(256) void k_fill(const int* __restrict__ ei,
                                              int* __restrict__ cursor,
                                              int* __restrict__ srcs) {
    int e = blockIdx.x * 256 + threadIdx.x;
    if (e >= NE) return;
    int r = ei[e];
    int c = ei[NE + e];
    int pos = atomicAdd(&cursor[c], 1);
    srcs[pos] = r;
}

// ---------------------------------------------------------------- GEMM t' = (relu?)(h) @ W * dinv[row]
// Block = 256 threads (4 waves), 64 rows per block. Thread: 8 rows x 4 cols.
template <bool RELU>
__global__ __launch_bounds__(256) void k_gemm(const float* __restrict__ h,
                                              const float* __restrict__ W,
                                              const float* __restrict__ dinv,
                                              float* __restrict__ t) {
    const int tid  = threadIdx.x;
    const int lane = tid & 63;
    const int wave = tid >> 6;
    const int colg = lane & 31;                 // 0..31 -> cols colg*4..+3
    const int rowg = (wave << 1) | (lane >> 5); // 0..7  -> 8 rows each
    const int rb   = blockIdx.x * 64 + rowg * 8;

    const float4* __restrict__ W4 = reinterpret_cast<const float4*>(W);

    float4 acc[8];
#pragma unroll
    for (int r = 0; r < 8; ++r) acc[r] = make_float4(0.f, 0.f, 0.f, 0.f);

    int rowid[8];
#pragma unroll
    for (int r = 0; r < 8; ++r) {
        int rr   = rb + r;
        rowid[r] = rr < NN ? rr : NN - 1;   // clamp loads, guard stores
    }

    for (int k0 = 0; k0 < H; k0 += 4) {
        float4 wv0 = W4[(k0 + 0) * 32 + colg];
        float4 wv1 = W4[(k0 + 1) * 32 + colg];
        float4 wv2 = W4[(k0 + 2) * 32 + colg];
        float4 wv3 = W4[(k0 + 3) * 32 + colg];
#pragma unroll
        for (int r = 0; r < 8; ++r) {
            float4 hv = *reinterpret_cast<const float4*>(h + (size_t)rowid[r] * H + k0);
            if (RELU) {
                hv.x = fmaxf(hv.x, 0.f); hv.y = fmaxf(hv.y, 0.f);
                hv.z = fmaxf(hv.z, 0.f); hv.w = fmaxf(hv.w, 0.f);
            }
            acc[r].x = fmaf(hv.x, wv0.x, fmaf(hv.y, wv1.x, fmaf(hv.z, wv2.x, fmaf(hv.w, wv3.x, acc[r].x))));
            acc[r].y = fmaf(hv.x, wv0.y, fmaf(hv.y, wv1.y, fmaf(hv.z, wv2.y, fmaf(hv.w, wv3.y, acc[r].y))));
            acc[r].z = fmaf(hv.x, wv0.z, fmaf(hv.y, wv1.z, fmaf(hv.z, wv2.z, fmaf(hv.w, wv3.z, acc[r].z))));
            acc[r].w = fmaf(hv.x, wv0.w, fmaf(hv.y, wv1.w, fmaf(hv.z, wv2.w, fmaf(hv.w, wv3.w, acc[r].w))));
        }
    }

#pragma unroll
    for (int r = 0; r < 8; ++r) {
        int rr = rb + r;
        if (rr < NN) {
            float d = dinv[rr];
            acc[r].x *= d; acc[r].y *= d; acc[r].z *= d; acc[r].w *= d;
            *reinterpret_cast<float4*>(t + (size_t)rr * H + colg * 4) = acc[r];
        }
    }
}

// ---------------------------------------------------------------- gather: agg[n] = bg + dinv[n] * (t'[n] + sum_e t'[src[e]])
// Half-wave (32 lanes x float4) per node; edge rows read from L2/L3.
__global__ __launch_bounds__(256) void k_gather(const int* __restrict__ rp,
                                                const int* __restrict__ cnt,
                                                const int* __restrict__ srcs,
                                                const float* __restrict__ dinv,
                                                const float* __restrict__ bg,
                                                const float* __restrict__ t,
                                                float* __restrict__ agg) {
    const int tid = threadIdx.x;
    const int n   = blockIdx.x * 8 + (tid >> 5);
    const int l32 = tid & 31;
    if (n >= NN) return;

    const float4* __restrict__ t4 = reinterpret_cast<const float4*>(t);
    float4 acc = t4[(size_t)n * 32 + l32];   // self-loop term (t' already has dinv[n])

    int i = rp[n];
    const int e = i + cnt[n];
    for (; i + 3 < e; i += 4) {
        int s0 = srcs[i], s1 = srcs[i + 1], s2 = srcs[i + 2], s3 = srcs[i + 3];
        float4 v0 = t4[(size_t)s0 * 32 + l32];
        float4 v1 = t4[(size_t)s1 * 32 + l32];
        float4 v2 = t4[(size_t)s2 * 32 + l32];
        float4 v3 = t4[(size_t)s3 * 32 + l32];
        acc.x += v0.x + v1.x + v2.x + v3.x;
        acc.y += v0.y + v1.y + v2.y + v3.y;
        acc.z += v0.z + v1.z + v2.z + v3.z;
        acc.w += v0.w + v1.w + v2.w + v3.w;
    }
    for (; i < e; ++i) {
        float4 v0 = t4[(size_t)srcs[i] * 32 + l32];
        acc.x += v0.x; acc.y += v0.y; acc.z += v0.z; acc.w += v0.w;
    }

    float d = dinv[n];
    float4 b = reinterpret_cast<const float4*>(bg)[l32];
    float4 o;
    o.x = fmaf(acc.x, d, b.x);
    o.y = fmaf(acc.y, d, b.y);
    o.z = fmaf(acc.z, d, b.z);
    o.w = fmaf(acc.w, d, b.w);
    reinterpret_cast<float4*>(agg)[(size_t)n * 32 + l32] = o;
}

// ---------------------------------------------------------------- mean pool (batch sorted -> binary search bounds)
__device__ __forceinline__ int lower_bound_dev(const int* __restrict__ b, int v) {
    int lo = 0, hi = NN;
    while (lo < hi) {
        int m = (lo + hi) >> 1;
        if (b[m] < v) lo = m + 1; else hi = m;
    }
    return lo;
}

__global__ __launch_bounds__(128) void k_pool(const int* __restrict__ batch,
                                              const float* __restrict__ agg,
                                              float* __restrict__ pooled,
                                              float* __restrict__ gcnt) {
    int g = blockIdx.x >> 3;   // 8 blocks per graph
    int q = blockIdx.x & 7;
    int tid = threadIdx.x;     // feature index
    int s = lower_bound_dev(batch, g);
    int e = lower_bound_dev(batch, g + 1);
    float sum = 0.f;
    for (int n = s + q; n < e; n += 8)
        sum += fmaxf(agg[(size_t)n * H + tid], 0.f);   // ReLU fused
    atomicAdd(&pooled[g * H + tid], sum);
    if (q == 0 && tid == 0) gcnt[g] = (float)(e - s);
}

// ---------------------------------------------------------------- LSTM (single step, h0=c0=0) + output head, fused
__global__ __launch_bounds__(256) void k_lstm(const float* __restrict__ pooled,
                                              const float* __restrict__ gcnt,
                                              const float* __restrict__ W_ih,
                                              const float* __restrict__ b_ih,
                                              const float* __restrict__ b_hh,
                                              const float* __restrict__ W_out,
                                              const float* __restrict__ b_out,
                                              float* __restrict__ out) {
    __shared__ __align__(16) float p[H];
    __shared__ __align__(16) float hn[LH];
    int g = blockIdx.x, t = threadIdx.x;
    if (t < H) p[t] = pooled[g * H + t] / fmaxf(gcnt[g], 1.f);
    __syncthreads();

    // gate rows (torch order i,f,g,o): f unused (c0=0)
    float si = b_ih[t] + b_hh[t];
    float sg = b_ih[2 * LH + t] + b_hh[2 * LH + t];
    float so = b_ih[3 * LH + t] + b_hh[3 * LH + t];
    const float* wi = W_ih + (size_t)t * H;
    const float* wg = W_ih + (size_t)(2 * LH + t) * H;
    const float* wo = W_ih + (size_t)(3 * LH + t) * H;
    for (int k = 0; k < H; k += 4) {
        float4 pv = *reinterpret_cast<const float4*>(&p[k]);
        float4 a = *reinterpret_cast<const float4*>(wi + k);
        si += pv.x * a.x + pv.y * a.y + pv.z * a.z + pv.w * a.w;
        float4 b = *reinterpret_cast<const float4*>(wg + k);
        sg += pv.x * b.x + pv.y * b.y + pv.z * b.z + pv.w * b.w;
        float4 c = *reinterpret_cast<const float4*>(wo + k);
        so += pv.x * c.x + pv.y * c.y + pv.z * c.z + pv.w * c.w;
    }
    float ig = 1.f / (1.f + expf(-si));
    float cc = ig * tanhf(sg);
    float og = 1.f / (1.f + expf(-so));
    hn[t] = og * tanhf(cc);
    __syncthreads();

    if (t < OD) {
        float acc = b_out[t];
        const float* wr = W_out + (size_t)t * LH;
        for (int k = 0; k < LH; k += 4) {
            float4 hv = *reinterpret_cast<const float4*>(&hn[k]);
            float4 wv = *reinterpret_cast<const float4*>(wr + k);
            acc += hv.x * wv.x + hv.y * wv.y + hv.z * wv.z + hv.w * wv.w;
        }
        out[g * OD + t] = acc;
    }
}

// ----------------------------------------------------------------
extern "C" void kernel_launch(void* const* d_in, const int* in_sizes, int n_in,
                              void* d_out, int out_size, void* d_ws, size_t ws_size,
                              hipStream_t stream) {
    const float* x     = (const float*)d_in[0];
    const int*   ei    = (const int*)d_in[1];   // [2][NE]: rows then cols
    const int*   batch = (const int*)d_in[2];
    const float* Wg    = (const float*)d_in[3]; // [3][128][128]
    const float* bg    = (const float*)d_in[4]; // [3][128]
    const float* W_ih  = (const float*)d_in[5]; // [1024][128]
    const float* b_ih  = (const float*)d_in[7];
    const float* b_hh  = (const float*)d_in[8];
    const float* W_out = (const float*)d_in[9]; // [32][256]
    const float* b_out = (const float*)d_in[10];
    float* out = (float*)d_out;

    // workspace layout (~59 MB)
    float* ws     = (float*)d_ws;
    float* buf0   = ws;                          // NN*H  (t')
    float* buf1   = buf0 + (size_t)NN * H;       // NN*H  (agg)
    float* dinv   = buf1 + (size_t)NN * H;       // NN
    float* pooled = dinv + NN;                   // NG*H
    float* gcnt   = pooled + NG * H;             // NG
    int*   cnt    = (int*)(gcnt + NG);           // NN
    int*   rp     = cnt + NN;                    // NN
    int*   cursor = rp + NN;                     // NN
    int*   srcs   = cursor + NN;                 // NE
    int*   bsum   = srcs + NE;                   // NB
    int*   boff   = bsum + 256;                  // NB

    hipMemsetAsync(cnt, 0, NN * sizeof(int), stream);
    hipMemsetAsync(pooled, 0, (NG * H + NG) * sizeof(float), stream);

    const int eBlocks = (NE + 255) / 256;

    // CSR build (by destination)
    k_hist <<<eBlocks, 256, 0, stream>>>(ei + NE, cnt);
    k_scan1<<<NB, 256, 0, stream>>>(cnt, bsum);
    k_scan2<<<1, 256, 0, stream>>>(bsum, boff);
    k_scan3<<<NB, 256, 0, stream>>>(cnt, boff, rp, cursor, dinv);
    k_fill <<<eBlocks, 256, 0, stream>>>(ei, cursor, srcs);

    const int gemmBlocks = (NN + 63) / 64;
    const int gathBlocks = (NN + 7) / 8;

    // layer 0: x -> buf0 -> buf1
    k_gemm<false><<<gemmBlocks, 256, 0, stream>>>(x, Wg, dinv, buf0);
    k_gather<<<gathBlocks, 256, 0, stream>>>(rp, cnt, srcs, dinv, bg, buf0, buf1);
    // layer 1: relu(buf1) -> buf0 -> buf1
    k_gemm<true><<<gemmBlocks, 256, 0, stream>>>(buf1, Wg + H * H, dinv, buf0);
    k_gather<<<gathBlocks, 256, 0, stream>>>(rp, cnt, srcs, dinv, bg + H, buf0, buf1);
    // layer 2: relu(buf1) -> buf0 -> buf1
    k_gemm<true><<<gemmBlocks, 256, 0, stream>>>(buf1, Wg + 2 * H * H, dinv, buf0);
    k_gather<<<gathBlocks, 256, 0, stream>>>(rp, cnt, srcs, dinv, bg + 2 * H, buf0, buf1);

    k_pool<<<NG * 8, 128, 0, stream>>>(batch, buf1, pooled, gcnt);
    k_lstm<<<NG, 256, 0, stream>>>(pooled, gcnt, W_ih, b_ih, b_hh, W_out, b_out, out);
}

// Round 6
// 590.697 us; speedup vs baseline: 14.1429x; 1.2320x over previous
//
#include <hip/hip_runtime.h>

// Problem constants (match reference setup_inputs)
constexpr int NN = 50000;     // nodes
constexpr int NE = 1600000;   // edges
constexpr int H  = 128;       // feature dim (F_IN == H)
constexpr int LH = 256;       // lstm hidden
constexpr int OD = 32;        // output dim
constexpr int NG = 64;        // graphs

// Bucketed CSR build: bucket = dst >> 8 (256 nodes per bucket)
constexpr int NBKT  = (NN + 255) / 256;           // 196
constexpr int PARTE = 4096;                       // edges per k_part block
constexpr int NPARTB = (NE + PARTE - 1) / PARTE;  // 391
static_assert(NBKT <= 256, "single-block scan assumes NBKT <= 256");

// ---------------------------------------------------------------- pass A: bucket histogram (LDS-aggregated)
__global__ __launch_bounds__(256) void k_bhist(const int* __restrict__ col,
                                               int* __restrict__ bktCnt) {
    __shared__ int h[NBKT];
    int t = threadIdx.x;
    if (t < NBKT) h[t] = 0;
    __syncthreads();
    for (int i = blockIdx.x * 256 + t; i < NE; i += gridDim.x * 256)
        atomicAdd(&h[col[i] >> 8], 1);
    __syncthreads();
    if (t < NBKT && h[t] > 0) atomicAdd(&bktCnt[t], h[t]);
}

// ---------------------------------------------------------------- pass B: scan bucket counts
__global__ __launch_bounds__(256) void k_bscan(const int* __restrict__ bktCnt,
                                               int* __restrict__ bktBase,
                                               int* __restrict__ bktCursor) {
    __shared__ int sh[256];
    int t = threadIdx.x;
    int v = (t < NBKT) ? bktCnt[t] : 0;
    sh[t] = v;
    __syncthreads();
    for (int off = 1; off < 256; off <<= 1) {
        int add = (t >= off) ? sh[t - off] : 0;
        __syncthreads();
        sh[t] += add;
        __syncthreads();
    }
    if (t < NBKT) {
        int excl = sh[t] - v;
        bktBase[t] = excl;
        bktCursor[t] = excl;
    }
    if (t == NBKT - 1) bktBase[NBKT] = sh[t];
}

// ---------------------------------------------------------------- pass C: partition edges into bucket-ordered (src,dst)
// One global atomic per (block, bucket) to reserve a range; ranks via LDS.
__global__ __launch_bounds__(256) void k_part(const int* __restrict__ ei,
                                              int* __restrict__ bktCursor,
                                              int2* __restrict__ part) {
    __shared__ int lcur[NBKT];
    __shared__ int lbase[NBKT];
    const int t = threadIdx.x;
    const int base = blockIdx.x * PARTE;
    int sr[16], ds[16], bk[16];

    if (t < NBKT) lcur[t] = 0;
    __syncthreads();
#pragma unroll
    for (int j = 0; j < 16; ++j) {
        int e = base + j * 256 + t;
        if (e < NE) {
            sr[j] = ei[e];
            ds[j] = ei[NE + e];
            bk[j] = ds[j] >> 8;
            atomicAdd(&lcur[bk[j]], 1);
        }
    }
    __syncthreads();
    if (t < NBKT) {
        int c = lcur[t];
        lbase[t] = (c > 0) ? atomicAdd(&bktCursor[t], c) : 0;
        lcur[t] = 0;
    }
    __syncthreads();
#pragma unroll
    for (int j = 0; j < 16; ++j) {
        int e = base + j * 256 + t;
        if (e < NE) {
            int r = atomicAdd(&lcur[bk[j]], 1);
            part[lbase[bk[j]] + r] = make_int2(sr[j], ds[j]);
        }
    }
}

// ---------------------------------------------------------------- pass D: per-bucket CSR finalize (all atomics in LDS)
__global__ __launch_bounds__(256) void k_bfill(const int* __restrict__ bktBase,
                                               const int2* __restrict__ part,
                                               int* __restrict__ rp,
                                               int* __restrict__ cnt,
                                               float* __restrict__ dinv,
                                               int* __restrict__ srcs) {
    __shared__ int h[256];
    __shared__ int sc[256];
    __shared__ int cur[256];
    const int b = blockIdx.x, t = threadIdx.x;
    const int lo = bktBase[b], hi = bktBase[b + 1];

    h[t] = 0;
    __syncthreads();
    for (int i = lo + t; i < hi; i += 256)
        atomicAdd(&h[part[i].y & 255], 1);
    __syncthreads();
    int v = h[t];
    sc[t] = v;
    __syncthreads();
    for (int off = 1; off < 256; off <<= 1) {
        int add = (t >= off) ? sc[t - off] : 0;
        __syncthreads();
        sc[t] += add;
        __syncthreads();
    }
    int excl = sc[t] - v;
    cur[t] = lo + excl;
    int node = b * 256 + t;
    if (node < NN) {
        rp[node] = lo + excl;
        cnt[node] = v;
        dinv[node] = rsqrtf((float)v + 1.0f);   // self-loop adds 1
    }
    __syncthreads();
    for (int i = lo + t; i < hi; i += 256) {
        int2 e = part[i];
        int pos = atomicAdd(&cur[e.y & 255], 1);
        srcs[pos] = e.x;
    }
}

// ---------------------------------------------------------------- GEMM t' = (relu?)(h) @ W * dinv[row]
// Block = 256 threads (4 waves), 64 rows per block. Thread: 8 rows x 4 cols.
template <bool RELU>
__global__ __launch_bounds__(256) void k_gemm(const float* __restrict__ h,
                                              const float* __restrict__ W,
                                              const float* __restrict__ dinv,
                                              float* __restrict__ t) {
    const int tid  = threadIdx.x;
    const int lane = tid & 63;
    const int wave = tid >> 6;
    const int colg = lane & 31;                 // 0..31 -> cols colg*4..+3
    const int rowg = (wave << 1) | (lane >> 5); // 0..7  -> 8 rows each
    const int rb   = blockIdx.x * 64 + rowg * 8;

    const float4* __restrict__ W4 = reinterpret_cast<const float4*>(W);

    float4 acc[8];
#pragma unroll
    for (int r = 0; r < 8; ++r) acc[r] = make_float4(0.f, 0.f, 0.f, 0.f);

    int rowid[8];
#pragma unroll
    for (int r = 0; r < 8; ++r) {
        int rr   = rb + r;
        rowid[r] = rr < NN ? rr : NN - 1;   // clamp loads, guard stores
    }

    for (int k0 = 0; k0 < H; k0 += 4) {
        float4 wv0 = W4[(k0 + 0) * 32 + colg];
        float4 wv1 = W4[(k0 + 1) * 32 + colg];
        float4 wv2 = W4[(k0 + 2) * 32 + colg];
        float4 wv3 = W4[(k0 + 3) * 32 + colg];
#pragma unroll
        for (int r = 0; r < 8; ++r) {
            float4 hv = *reinterpret_cast<const float4*>(h + (size_t)rowid[r] * H + k0);
            if (RELU) {
                hv.x = fmaxf(hv.x, 0.f); hv.y = fmaxf(hv.y, 0.f);
                hv.z = fmaxf(hv.z, 0.f); hv.w = fmaxf(hv.w, 0.f);
            }
            acc[r].x = fmaf(hv.x, wv0.x, fmaf(hv.y, wv1.x, fmaf(hv.z, wv2.x, fmaf(hv.w, wv3.x, acc[r].x))));
            acc[r].y = fmaf(hv.x, wv0.y, fmaf(hv.y, wv1.y, fmaf(hv.z, wv2.y, fmaf(hv.w, wv3.y, acc[r].y))));
            acc[r].z = fmaf(hv.x, wv0.z, fmaf(hv.y, wv1.z, fmaf(hv.z, wv2.z, fmaf(hv.w, wv3.z, acc[r].z))));
            acc[r].w = fmaf(hv.x, wv0.w, fmaf(hv.y, wv1.w, fmaf(hv.z, wv2.w, fmaf(hv.w, wv3.w, acc[r].w))));
        }
    }

#pragma unroll
    for (int r = 0; r < 8; ++r) {
        int rr = rb + r;
        if (rr < NN) {
            float d = dinv[rr];
            acc[r].x *= d; acc[r].y *= d; acc[r].z *= d; acc[r].w *= d;
            *reinterpret_cast<float4*>(t + (size_t)rr * H + colg * 4) = acc[r];
        }
    }
}

// ---------------------------------------------------------------- gather: agg[n] = bg + dinv[n] * (t'[n] + sum_e t'[src[e]])
// Half-wave (32 lanes x float4) per node; edge rows read from L2/L3.
__global__ __launch_bounds__(256) void k_gather(const int* __restrict__ rp,
                                                const int* __restrict__ cnt,
                                                const int* __restrict__ srcs,
                                                const float* __restrict__ dinv,
                                                const float* __restrict__ bg,
                                                const float* __restrict__ t,
                                                float* __restrict__ agg) {
    const int tid = threadIdx.x;
    const int n   = blockIdx.x * 8 + (tid >> 5);
    const int l32 = tid & 31;
    if (n >= NN) return;

    const float4* __restrict__ t4 = reinterpret_cast<const float4*>(t);
    float4 acc = t4[(size_t)n * 32 + l32];   // self-loop term (t' already has dinv[n])

    int i = rp[n];
    const int e = i + cnt[n];
    for (; i + 3 < e; i += 4) {
        int s0 = srcs[i], s1 = srcs[i + 1], s2 = srcs[i + 2], s3 = srcs[i + 3];
        float4 v0 = t4[(size_t)s0 * 32 + l32];
        float4 v1 = t4[(size_t)s1 * 32 + l32];
        float4 v2 = t4[(size_t)s2 * 32 + l32];
        float4 v3 = t4[(size_t)s3 * 32 + l32];
        acc.x += v0.x + v1.x + v2.x + v3.x;
        acc.y += v0.y + v1.y + v2.y + v3.y;
        acc.z += v0.z + v1.z + v2.z + v3.z;
        acc.w += v0.w + v1.w + v2.w + v3.w;
    }
    for (; i < e; ++i) {
        float4 v0 = t4[(size_t)srcs[i] * 32 + l32];
        acc.x += v0.x; acc.y += v0.y; acc.z += v0.z; acc.w += v0.w;
    }

    float d = dinv[n];
    float4 b = reinterpret_cast<const float4*>(bg)[l32];
    float4 o;
    o.x = fmaf(acc.x, d, b.x);
    o.y = fmaf(acc.y, d, b.y);
    o.z = fmaf(acc.z, d, b.z);
    o.w = fmaf(acc.w, d, b.w);
    reinterpret_cast<float4*>(agg)[(size_t)n * 32 + l32] = o;
}

// ---------------------------------------------------------------- mean pool (batch sorted -> binary search bounds)
__device__ __forceinline__ int lower_bound_dev(const int* __restrict__ b, int v) {
    int lo = 0, hi = NN;
    while (lo < hi) {
        int m = (lo + hi) >> 1;
        if (b[m] < v) lo = m + 1; else hi = m;
    }
    return lo;
}

__global__ __launch_bounds__(128) void k_pool(const int* __restrict__ batch,
                                              const float* __restrict__ agg,
                                              float* __restrict__ pooled,
                                              float* __restrict__ gcnt) {
    int g = blockIdx.x >> 3;   // 8 blocks per graph
    int q = blockIdx.x & 7;
    int tid = threadIdx.x;     // feature index
    int s = lower_bound_dev(batch, g);
    int e = lower_bound_dev(batch, g + 1);
    float sum = 0.f;
    for (int n = s + q; n < e; n += 8)
        sum += fmaxf(agg[(size_t)n * H + tid], 0.f);   // ReLU fused
    atomicAdd(&pooled[g * H + tid], sum);
    if (q == 0 && tid == 0) gcnt[g] = (float)(e - s);
}

// ---------------------------------------------------------------- LSTM (single step, h0=c0=0) + output head, fused
__global__ __launch_bounds__(256) void k_lstm(const float* __restrict__ pooled,
                                              const float* __restrict__ gcnt,
                                              const float* __restrict__ W_ih,
                                              const float* __restrict__ b_ih,
                                              const float* __restrict__ b_hh,
                                              const float* __restrict__ W_out,
                                              const float* __restrict__ b_out,
                                              float* __restrict__ out) {
    __shared__ __align__(16) float p[H];
    __shared__ __align__(16) float hn[LH];
    int g = blockIdx.x, t = threadIdx.x;
    if (t < H) p[t] = pooled[g * H + t] / fmaxf(gcnt[g], 1.f);
    __syncthreads();

    // gate rows (torch order i,f,g,o): f unused (c0=0)
    float si = b_ih[t] + b_hh[t];
    float sg = b_ih[2 * LH + t] + b_hh[2 * LH + t];
    float so = b_ih[3 * LH + t] + b_hh[3 * LH + t];
    const float* wi = W_ih + (size_t)t * H;
    const float* wg = W_ih + (size_t)(2 * LH + t) * H;
    const float* wo = W_ih + (size_t)(3 * LH + t) * H;
    for (int k = 0; k < H; k += 4) {
        float4 pv = *reinterpret_cast<const float4*>(&p[k]);
        float4 a = *reinterpret_cast<const float4*>(wi + k);
        si += pv.x * a.x + pv.y * a.y + pv.z * a.z + pv.w * a.w;
        float4 b = *reinterpret_cast<const float4*>(wg + k);
        sg += pv.x * b.x + pv.y * b.y + pv.z * b.z + pv.w * b.w;
        float4 c = *reinterpret_cast<const float4*>(wo + k);
        so += pv.x * c.x + pv.y * c.y + pv.z * c.z + pv.w * c.w;
    }
    float ig = 1.f / (1.f + expf(-si));
    float cc = ig * tanhf(sg);
    float og = 1.f / (1.f + expf(-so));
    hn[t] = og * tanhf(cc);
    __syncthreads();

    if (t < OD) {
        float acc = b_out[t];
        const float* wr = W_out + (size_t)t * LH;
        for (int k = 0; k < LH; k += 4) {
            float4 hv = *reinterpret_cast<const float4*>(&hn[k]);
            float4 wv = *reinterpret_cast<const float4*>(wr + k);
            acc += hv.x * wv.x + hv.y * wv.y + hv.z * wv.z + hv.w * wv.w;
        }
        out[g * OD + t] = acc;
    }
}

// ----------------------------------------------------------------
extern "C" void kernel_launch(void* const* d_in, const int* in_sizes, int n_in,
                              void* d_out, int out_size, void* d_ws, size_t ws_size,
                              hipStream_t stream) {
    const float* x     = (const float*)d_in[0];
    const int*   ei    = (const int*)d_in[1];   // [2][NE]: rows then cols
    const int*   batch = (const int*)d_in[2];
    const float* Wg    = (const float*)d_in[3]; // [3][128][128]
    const float* bg    = (const float*)d_in[4]; // [3][128]
    const float* W_ih  = (const float*)d_in[5]; // [1024][128]
    const float* b_ih  = (const float*)d_in[7];
    const float* b_hh  = (const float*)d_in[8];
    const float* W_out = (const float*)d_in[9]; // [32][256]
    const float* b_out = (const float*)d_in[10];
    float* out = (float*)d_out;

    // workspace layout (~71 MB)
    float* ws        = (float*)d_ws;
    float* buf0      = ws;                           // NN*H  (t')
    float* buf1      = buf0 + (size_t)NN * H;        // NN*H  (agg)
    int2*  part      = (int2*)(buf1 + (size_t)NN * H); // NE int2 (8B-aligned: 12.8M floats precede)
    float* dinv      = (float*)(part + NE);          // NN
    float* pooled    = dinv + NN;                    // NG*H
    float* gcnt      = pooled + NG * H;              // NG
    int*   cnt       = (int*)(gcnt + NG);            // NN
    int*   rp        = cnt + NN;                     // NN
    int*   srcs      = rp + NN;                      // NE
    int*   bktCnt    = srcs + NE;                    // NBKT
    int*   bktBase   = bktCnt + NBKT;                // NBKT+1
    int*   bktCursor = bktBase + NBKT + 1;           // NBKT

    hipMemsetAsync(bktCnt, 0, NBKT * sizeof(int), stream);
    hipMemsetAsync(pooled, 0, (NG * H + NG) * sizeof(float), stream);

    // CSR build (by destination) — bucketed counting sort
    k_bhist<<<256, 256, 0, stream>>>(ei + NE, bktCnt);
    k_bscan<<<1, 256, 0, stream>>>(bktCnt, bktBase, bktCursor);
    k_part <<<NPARTB, 256, 0, stream>>>(ei, bktCursor, part);
    k_bfill<<<NBKT, 256, 0, stream>>>(bktBase, part, rp, cnt, dinv, srcs);

    const int gemmBlocks = (NN + 63) / 64;
    const int gathBlocks = (NN + 7) / 8;

    // layer 0: x -> buf0 -> buf1
    k_gemm<false><<<gemmBlocks, 256, 0, stream>>>(x, Wg, dinv, buf0);
    k_gather<<<gathBlocks, 256, 0, stream>>>(rp, cnt, srcs, dinv, bg, buf0, buf1);
    // layer 1: relu(buf1) -> buf0 -> buf1
    k_gemm<true><<<gemmBlocks, 256, 0, stream>>>(buf1, Wg + H * H, dinv, buf0);
    k_gather<<<gathBlocks, 256, 0, stream>>>(rp, cnt, srcs, dinv, bg + H, buf0, buf1);
    // layer 2: relu(buf1) -> buf0 -> buf1
    k_gemm<true><<<gemmBlocks, 256, 0, stream>>>(buf1, Wg + 2 * H * H, dinv, buf0);
    k_gather<<<gathBlocks, 256, 0, stream>>>(rp, cnt, srcs, dinv, bg + 2 * H, buf0, buf1);

    k_pool<<<NG * 8, 128, 0, stream>>>(batch, buf1, pooled, gcnt);
    k_lstm<<<NG, 256, 0, stream>>>(pooled, gcnt, W_ih, b_ih, b_hh, W_out, b_out, out);
}